// Round 7
// baseline (508.881 us; speedup 1.0000x reference)
//
#include <hip/hip_runtime.h>

namespace {
constexpr int kB  = 2;
constexpr int kNC = 4096;
constexpr int kNT = 1024;
constexpr int kDX = 64;
constexpr int kK  = 32;
constexpr int kNQ = kB * (kNC + kNT);            // 10240
constexpr long long kE = (long long)kNQ * kK;    // 327680
constexpr int QPW  = 4;                          // queries per wave
constexpr int WAVES = 4;                         // waves per block
constexpr int QPB  = WAVES * QPW;                // 16 queries per block
constexpr int TILE = 64;                         // refs per LDS tile
constexpr int HALF = 2048;                       // refs per split-K block
constexpr int HT   = HALF / TILE;                // 32 tiles per half
// inf stand-in: must stay finite after bf16 round-trip (FLT_MAX -> bf16 inf)
constexpr float kBigFinite = 1e30f;
// ws layout: rn[8192] floats, then keys[kNQ][2][32] u64
constexpr size_t kRNF     = 8192;
constexpr size_t kKeyOffB = kRNF * 4;
constexpr size_t kWsNeed  = kKeyOffB + (size_t)kNQ * 64 * 8;
}

__device__ __forceinline__ void resolve_q(int gid,
    const float* x_ctx, const float* s_ctx, const float* t_ctx,
    const float* x_test, const float* s_test, const float* t_test,
    int& b, const float*& qx, const float*& qs, const float*& qt)
{
    if (gid < kB * kNC) {
        b  = gid >> 12;
        qx = x_ctx + (size_t)gid * kDX;
        qs = s_ctx + (size_t)gid * 3;
        qt = t_ctx + gid;
    } else {
        const int g2 = gid - kB * kNC;
        b  = g2 >> 10;
        qx = x_test + (size_t)g2 * kDX;
        qs = s_test + (size_t)g2 * 3;
        qt = t_test + g2;
    }
}

// Exact online insert into wave-held sorted ascending top-32 (validated r4-r6).
__device__ __forceinline__ void insert_half(unsigned long long& listKey,
    unsigned long long keyQ, int lane, int base)
{
    const unsigned long long thr = __shfl(listKey, base + 31, 64);
    unsigned long long hb = __ballot(keyQ < thr);
    while (hb) {
        const int srcl = __ffsll((unsigned long long)hb) - 1;
        hb &= hb - 1;
        const unsigned long long K = __shfl(keyQ, srcl, 64);
        const unsigned long long lt = __ballot(listKey < K);
        const unsigned int half = base ? (unsigned int)(lt >> 32)
                                       : (unsigned int)lt;
        const int pos = __popc(half) + base;
        if (pos < base + 32) {
            const unsigned long long up = __shfl_up(listKey, 1, 64);
            if (lane >= base && lane < base + 32) {
                if (lane > pos)       listKey = up;
                else if (lane == pos) listKey = K;
            }
        }
    }
}

// ---- prep: rn[row] with the exact validated fmaf chain (validated r5) ----
__global__ __launch_bounds__(256)
void prep_rn(const float* __restrict__ x, float* __restrict__ ws)
{
    const int r = blockIdx.x * 256 + threadIdx.x;    // 0..8191
    const float4* xr = (const float4*)(x + (size_t)r * kDX);
    float rn = 0.f;
    #pragma unroll
    for (int j = 0; j < 16; ++j) {
        const float4 rv = xr[j];
        rn = fmaf(rv.x, rv.x, rn); rn = fmaf(rv.y, rv.y, rn);
        rn = fmaf(rv.z, rv.z, rn); rn = fmaf(rv.w, rv.w, rn);
    }
    ws[r] = rn;
}

// ---- split-K main: each block scans HALF refs for 16 queries, emits keys ----
__global__ __launch_bounds__(256, 5)
void knn_v5_part(const float* __restrict__ x_ctx, const float* __restrict__ s_ctx,
                 const float* __restrict__ t_ctx, const unsigned char* __restrict__ mask_ctx,
                 const float* __restrict__ x_test, const float* __restrict__ s_test,
                 const float* __restrict__ t_test, const float* __restrict__ rn_ws,
                 unsigned long long* __restrict__ keys)
{
    __shared__ float4 xt[2][TILE * 16];   // 2 x 16KB double-buffered ref tiles

    const int tid  = threadIdx.x;
    const int lane = tid & 63;
    const int w    = __builtin_amdgcn_readfirstlane(tid >> 6);
    const int blk  = blockIdx.x;          // 1280
    const int g    = blk >> 1;            // query group 0..639
    const int h    = blk & 1;             // ref half
    const int qbase = g * QPB;
    const int gid0  = qbase + w * QPW;

    int b;
    { int b_; const float *a, *c, *d;
      resolve_q(qbase, x_ctx, s_ctx, t_ctx, x_test, s_test, t_test, b_, a, c, d);
      b = b_; }

    const float4* xb4 = (const float4*)x_ctx + (size_t)b * kNC * (kDX / 4);
    const float*  rsp = s_ctx + (size_t)b * kNC * 3;
    const float*  rtp = t_ctx + (size_t)b * kNC;
    const float*  rnp = rn_ws + (size_t)b * kNC;
    const unsigned char* mp = mask_ctx + (size_t)b * kNC;

    // ---- per-wave query setup (4 queries; pointers wave-uniform) ----
    const float* qxp[QPW];
    float qs0[QPW], qs1[QPW], qs2[QPW], qsn[QPW], qtv[QPW], qn[QPW];
    #pragma unroll
    for (int q = 0; q < QPW; ++q) {
        int bb; const float *qx, *qs, *qt;
        resolve_q(gid0 + q, x_ctx, s_ctx, t_ctx, x_test, s_test, t_test,
                  bb, qx, qs, qt);
        qxp[q] = qx;
        qs0[q] = qs[0]; qs1[q] = qs[1]; qs2[q] = qs[2]; qtv[q] = qt[0];
        qsn[q] = qs0[q]*qs0[q] + qs1[q]*qs1[q] + qs2[q]*qs2[q];
        const float ql = qx[lane];
        float s = ql * ql;
        #pragma unroll
        for (int off = 32; off > 0; off >>= 1) s += __shfl_xor(s, off, 64);
        qn[q] = s;
    }

    // staging geometry: 4 float4 per thread per tile, XOR-swizzled LDS dest
    int sg[4], ss[4];
    #pragma unroll
    for (int i = 0; i < 4; ++i) {
        const int n = tid + 256 * i;
        const int r = n >> 4, j = n & 15;
        sg[i] = n;
        ss[i] = (r << 4) | (j ^ (r & 7));
    }
    const size_t hbase = (size_t)h * (HALF * 16);   // float4 offset of this half
    #pragma unroll
    for (int i = 0; i < 4; ++i) xt[0][ss[i]] = xb4[hbase + sg[i]];
    __syncthreads();

    const int lbase = lane << 4, lsw = lane & 7;
    const float INF = __builtin_inff();
    unsigned long long lst01 = ~0ull, lst23 = ~0ull;

    for (int t = 0; t < HT; ++t) {
        float4 p0, p1, p2, p3;
        const bool pre = (t + 1 < HT);
        if (pre) {
            const size_t nb = hbase + (size_t)(t + 1) * 1024;
            p0 = xb4[nb + sg[0]]; p1 = xb4[nb + sg[1]];
            p2 = xb4[nb + sg[2]]; p3 = xb4[nb + sg[3]];
        }
        const float4* buf = xt[t & 1];

        float dot[QPW] = {0.f, 0.f, 0.f, 0.f};
        #pragma unroll
        for (int j = 0; j < 16; ++j) {
            const float4 rv = buf[lbase | (j ^ lsw)];
            #pragma unroll
            for (int q = 0; q < QPW; ++q) {
                const float4 qv = ((const float4*)qxp[q])[j];   // s_load (uniform)
                dot[q] = fmaf(qv.x, rv.x, dot[q]);
                dot[q] = fmaf(qv.y, rv.y, dot[q]);
                dot[q] = fmaf(qv.z, rv.z, dot[q]);
                dot[q] = fmaf(qv.w, rv.w, dot[q]);
            }
        }

        const int r = h * HALF + t * TILE + lane;
        const float rn  = rnp[r];                       // exact chain via prep_rn
        const float rs0 = rsp[r*3+0], rs1 = rsp[r*3+1], rs2 = rsp[r*3+2];
        const float rtv = rtp[r];
        const bool  m   = (mp[r] != 0);
        const float rsn = rs0*rs0 + rs1*rs1 + rs2*rs2;

        #pragma unroll
        for (int q = 0; q < QPW; ++q) {
            float d_x = qn[q] + rn - 2.0f * dot[q];
            const float sdot = qs0[q]*rs0 + qs1[q]*rs1 + qs2[q]*rs2;
            float d_s = qsn[q] + rsn - 2.0f * sdot;
            float d_t = rtv - qtv[q];
            if (!m) { d_x = INF; d_s = INF; d_t = INF; }
            if (!(d_t <= 0.f)) d_t = INF;
            const float v = d_x*d_x + d_s*d_s + d_t*d_t;
            const unsigned long long key =
                ((unsigned long long)__float_as_uint(v) << 32) | (unsigned)r;
            if (q < 2) insert_half(lst01, key, lane, (q & 1) * 32);
            else       insert_half(lst23, key, lane, (q & 1) * 32);
        }

        if (pre) {
            float4* nbuf = xt[(t + 1) & 1];
            nbuf[ss[0]] = p0; nbuf[ss[1]] = p1;
            nbuf[ss[2]] = p2; nbuf[ss[3]] = p3;
        }
        __syncthreads();
    }

    // ---- write per-half sorted key lists: keys[gid][h][slot] ----
    #pragma unroll
    for (int p = 0; p < 2; ++p) {
        const unsigned long long key = p ? lst23 : lst01;
        const int qidx = 2 * p + (lane >> 5);
        keys[((size_t)(gid0 + qidx) * 2 + h) * 32 + (lane & 31)] = key;
    }
}

// ---- merge two sorted 32-lists per query + validated emit ----
__global__ __launch_bounds__(256)
void knn_v5_merge(const float* __restrict__ x_ctx, const float* __restrict__ s_ctx,
                  const float* __restrict__ t_ctx, const unsigned char* __restrict__ mask_ctx,
                  const float* __restrict__ x_test, const float* __restrict__ s_test,
                  const float* __restrict__ t_test,
                  const unsigned long long* __restrict__ keys,
                  float* __restrict__ out)
{
    __shared__ unsigned long long kbuf[WAVES][64];
    __shared__ unsigned long long merged[WAVES][32];

    const int tid  = threadIdx.x;
    const int lane = tid & 63;
    const int w    = tid >> 6;
    const int qid  = blockIdx.x * WAVES + w;    // grid 2560 -> 10240 queries

    int b; const float *qx, *qs, *qt;
    resolve_q(qid, x_ctx, s_ctx, t_ctx, x_test, s_test, t_test, b, qx, qs, qt);
    const float qs0_ = qs[0], qs1_ = qs[1], qs2_ = qs[2], qtv_ = qt[0];
    const float qsn_ = qs0_*qs0_ + qs1_*qs1_ + qs2_*qs2_;
    const float ql = qx[lane];
    float qn_ = ql * ql;
    #pragma unroll
    for (int off = 32; off > 0; off >>= 1) qn_ += __shfl_xor(qn_, off, 64);

    // lane<32 holds half-0 list, lane>=32 holds half-1 list (both ascending)
    const unsigned long long mykey = keys[(size_t)qid * 64 + lane];
    kbuf[w][lane] = mykey;
    __syncthreads();

    int cnt = 0;
    const int ob = (lane < 32) ? 32 : 0;
    #pragma unroll
    for (int j = 0; j < 32; ++j) cnt += (kbuf[w][ob + j] < mykey) ? 1 : 0;
    const int pos = (lane & 31) + cnt;          // global rank (keys unique)
    if (pos < 32) merged[w][pos] = mykey;
    __syncthreads();

    if (lane < kK) {
        const unsigned long long key = merged[w][lane];
        const int rsel = (int)(key & 0xFFFFFFFFull);

        const float*  rsp = s_ctx + (size_t)b * kNC * 3;
        const float*  rtp = t_ctx + (size_t)b * kNC;
        const unsigned char* mp = mask_ctx + (size_t)b * kNC;

        const float4* xr = (const float4*)(x_ctx + ((size_t)b * kNC + rsel) * kDX);
        const float4* qr = (const float4*)qx;
        float dot = 0.f, rn2 = 0.f;
        #pragma unroll
        for (int j = 0; j < 16; ++j) {
            const float4 rv = xr[j];
            const float4 qv = qr[j];
            rn2 = fmaf(rv.x, rv.x, rn2); rn2 = fmaf(rv.y, rv.y, rn2);
            rn2 = fmaf(rv.z, rv.z, rn2); rn2 = fmaf(rv.w, rv.w, rn2);
            dot = fmaf(qv.x, rv.x, dot); dot = fmaf(qv.y, rv.y, dot);
            dot = fmaf(qv.z, rv.z, dot); dot = fmaf(qv.w, rv.w, dot);
        }
        float d_x = qn_ + rn2 - 2.0f * dot;
        const float rs0 = rsp[rsel*3+0], rs1 = rsp[rsel*3+1], rs2 = rsp[rsel*3+2];
        const float rsn = rs0*rs0 + rs1*rs1 + rs2*rs2;
        const float sdot = qs0_*rs0 + qs1_*rs1 + qs2_*rs2;
        float d_s = qsn_ + rsn - 2.0f * sdot;
        const float dt_raw = rtp[rsel] - qtv_;
        const bool  m = (mp[rsel] != 0);
        const bool  causal = m && (dt_raw <= 0.f);

        const float em = causal ? 1.0f : 0.0f;
        const float d_x_out = m ? d_x : kBigFinite;
        const float d_s_out = m ? d_s : kBigFinite;
        const float d_t_out = causal ? dt_raw : kBigFinite;

        const size_t e = (size_t)qid * kK + (size_t)lane;
        out[e]                = (float)(rsel + b * kNC);
        out[(size_t)kE   + e] = (float)qid;
        out[(size_t)kE*2 + e] = d_x_out;
        out[(size_t)kE*3 + e] = d_s_out;
        out[(size_t)kE*4 + e] = d_t_out;
        out[(size_t)kE*5 + e] = em;
    }
}

// ================= fallback: validated round-6 kernel (v4) =================
__global__ __launch_bounds__(256, 4)
void knn_v4(const float* __restrict__ x_ctx, const float* __restrict__ s_ctx,
            const float* __restrict__ t_ctx, const unsigned char* __restrict__ mask_ctx,
            const float* __restrict__ x_test, const float* __restrict__ s_test,
            const float* __restrict__ t_test, float* __restrict__ out)
{
    __shared__ float4 xt[2][TILE * 16];
    const int tid  = threadIdx.x;
    const int lane = tid & 63;
    const int w    = __builtin_amdgcn_readfirstlane(tid >> 6);
    const int qbase = blockIdx.x * QPB;
    const int gid0  = qbase + w * QPW;
    int b;
    { int b_; const float *a, *c, *d;
      resolve_q(qbase, x_ctx, s_ctx, t_ctx, x_test, s_test, t_test, b_, a, c, d);
      b = b_; }
    const float4* xb4 = (const float4*)x_ctx + (size_t)b * kNC * (kDX / 4);
    const float*  rsp = s_ctx + (size_t)b * kNC * 3;
    const float*  rtp = t_ctx + (size_t)b * kNC;
    const unsigned char* mp = mask_ctx + (size_t)b * kNC;
    const float* qxp[QPW];
    float qs0[QPW], qs1[QPW], qs2[QPW], qsn[QPW], qtv[QPW], qn[QPW];
    #pragma unroll
    for (int q = 0; q < QPW; ++q) {
        int bb; const float *qx, *qs, *qt;
        resolve_q(gid0 + q, x_ctx, s_ctx, t_ctx, x_test, s_test, t_test, bb, qx, qs, qt);
        qxp[q] = qx;
        qs0[q] = qs[0]; qs1[q] = qs[1]; qs2[q] = qs[2]; qtv[q] = qt[0];
        qsn[q] = qs0[q]*qs0[q] + qs1[q]*qs1[q] + qs2[q]*qs2[q];
        const float ql = qx[lane];
        float s = ql * ql;
        #pragma unroll
        for (int off = 32; off > 0; off >>= 1) s += __shfl_xor(s, off, 64);
        qn[q] = s;
    }
    int sg[4], ss[4];
    #pragma unroll
    for (int i = 0; i < 4; ++i) {
        const int n = tid + 256 * i;
        const int r = n >> 4, j = n & 15;
        sg[i] = n; ss[i] = (r << 4) | (j ^ (r & 7));
    }
    #pragma unroll
    for (int i = 0; i < 4; ++i) xt[0][ss[i]] = xb4[sg[i]];
    __syncthreads();
    const int lbase = lane << 4, lsw = lane & 7;
    const float INF = __builtin_inff();
    unsigned long long lst01 = ~0ull, lst23 = ~0ull;
    for (int t = 0; t < kNC / TILE; ++t) {
        float4 p0, p1, p2, p3;
        const bool pre = (t + 1 < kNC / TILE);
        if (pre) {
            const size_t nb = (size_t)(t + 1) * 1024;
            p0 = xb4[nb + sg[0]]; p1 = xb4[nb + sg[1]];
            p2 = xb4[nb + sg[2]]; p3 = xb4[nb + sg[3]];
        }
        const float4* buf = xt[t & 1];
        float dot[QPW] = {0.f, 0.f, 0.f, 0.f};
        float rn = 0.f;
        #pragma unroll
        for (int j = 0; j < 16; ++j) {
            const float4 rv = buf[lbase | (j ^ lsw)];
            rn = fmaf(rv.x, rv.x, rn); rn = fmaf(rv.y, rv.y, rn);
            rn = fmaf(rv.z, rv.z, rn); rn = fmaf(rv.w, rv.w, rn);
            #pragma unroll
            for (int q = 0; q < QPW; ++q) {
                const float4 qv = ((const float4*)qxp[q])[j];
                dot[q] = fmaf(qv.x, rv.x, dot[q]);
                dot[q] = fmaf(qv.y, rv.y, dot[q]);
                dot[q] = fmaf(qv.z, rv.z, dot[q]);
                dot[q] = fmaf(qv.w, rv.w, dot[q]);
            }
        }
        const int r = t * TILE + lane;
        const float rs0 = rsp[r*3+0], rs1 = rsp[r*3+1], rs2 = rsp[r*3+2];
        const float rtv = rtp[r];
        const bool  m   = (mp[r] != 0);
        const float rsn = rs0*rs0 + rs1*rs1 + rs2*rs2;
        #pragma unroll
        for (int q = 0; q < QPW; ++q) {
            float d_x = qn[q] + rn - 2.0f * dot[q];
            const float sdot = qs0[q]*rs0 + qs1[q]*rs1 + qs2[q]*rs2;
            float d_s = qsn[q] + rsn - 2.0f * sdot;
            float d_t = rtv - qtv[q];
            if (!m) { d_x = INF; d_s = INF; d_t = INF; }
            if (!(d_t <= 0.f)) d_t = INF;
            const float v = d_x*d_x + d_s*d_s + d_t*d_t;
            const unsigned long long key =
                ((unsigned long long)__float_as_uint(v) << 32) | (unsigned)r;
            if (q < 2) insert_half(lst01, key, lane, (q & 1) * 32);
            else       insert_half(lst23, key, lane, (q & 1) * 32);
        }
        if (pre) {
            float4* nbuf = xt[(t + 1) & 1];
            nbuf[ss[0]] = p0; nbuf[ss[1]] = p1;
            nbuf[ss[2]] = p2; nbuf[ss[3]] = p3;
        }
        __syncthreads();
    }
    #pragma unroll
    for (int p = 0; p < 2; ++p) {
        const unsigned long long myl = p ? lst23 : lst01;
        const int qidx = 2 * p + (lane >> 5);
        const int rsel = (int)(myl & 0xFFFFFFFFull);
        const int gid  = gid0 + qidx;
        const float* qx  = (lane < 32) ? qxp[2*p] : qxp[2*p+1];
        const float qn_  = (lane < 32) ? qn [2*p] : qn [2*p+1];
        const float qs0_ = (lane < 32) ? qs0[2*p] : qs0[2*p+1];
        const float qs1_ = (lane < 32) ? qs1[2*p] : qs1[2*p+1];
        const float qs2_ = (lane < 32) ? qs2[2*p] : qs2[2*p+1];
        const float qsn_ = (lane < 32) ? qsn[2*p] : qsn[2*p+1];
        const float qtv_ = (lane < 32) ? qtv[2*p] : qtv[2*p+1];
        const float4* xr = (const float4*)(x_ctx + ((size_t)b * kNC + rsel) * kDX);
        const float4* qr = (const float4*)qx;
        float dot = 0.f, rn2 = 0.f;
        #pragma unroll
        for (int j = 0; j < 16; ++j) {
            const float4 rv = xr[j];
            const float4 qv = qr[j];
            rn2 = fmaf(rv.x, rv.x, rn2); rn2 = fmaf(rv.y, rv.y, rn2);
            rn2 = fmaf(rv.z, rv.z, rn2); rn2 = fmaf(rv.w, rv.w, rn2);
            dot = fmaf(qv.x, rv.x, dot); dot = fmaf(qv.y, rv.y, dot);
            dot = fmaf(qv.z, rv.z, dot); dot = fmaf(qv.w, rv.w, dot);
        }
        float d_x = qn_ + rn2 - 2.0f * dot;
        const float rs0 = rsp[rsel*3+0], rs1 = rsp[rsel*3+1], rs2 = rsp[rsel*3+2];
        const float rsn = rs0*rs0 + rs1*rs1 + rs2*rs2;
        const float sdot = qs0_*rs0 + qs1_*rs1 + qs2_*rs2;
        float d_s = qsn_ + rsn - 2.0f * sdot;
        const float dt_raw = rtp[rsel] - qtv_;
        const bool  m = (mp[rsel] != 0);
        const bool  causal = m && (dt_raw <= 0.f);
        const float em = causal ? 1.0f : 0.0f;
        const size_t e = (size_t)gid * kK + (size_t)(lane & 31);
        out[e]                = (float)(rsel + b * kNC);
        out[(size_t)kE   + e] = (float)gid;
        out[(size_t)kE*2 + e] = m ? d_x : kBigFinite;
        out[(size_t)kE*3 + e] = m ? d_s : kBigFinite;
        out[(size_t)kE*4 + e] = causal ? dt_raw : kBigFinite;
        out[(size_t)kE*5 + e] = em;
    }
}

extern "C" void kernel_launch(void* const* d_in, const int* in_sizes, int n_in,
                              void* d_out, int out_size, void* d_ws, size_t ws_size,
                              hipStream_t stream) {
    (void)in_sizes; (void)n_in; (void)out_size;
    const float* x_ctx = (const float*)d_in[0];
    const float* s_ctx = (const float*)d_in[1];
    const float* t_ctx = (const float*)d_in[2];
    const unsigned char* mask_ctx = (const unsigned char*)d_in[3];
    const float* x_test = (const float*)d_in[4];
    const float* s_test = (const float*)d_in[5];
    const float* t_test = (const float*)d_in[6];

    if (ws_size >= kWsNeed) {
        float* rn_ws = (float*)d_ws;
        unsigned long long* keys =
            (unsigned long long*)((char*)d_ws + kKeyOffB);
        prep_rn<<<dim3(32), dim3(256), 0, stream>>>(x_ctx, rn_ws);
        knn_v5_part<<<dim3(2 * kNQ / QPB), dim3(256), 0, stream>>>(
            x_ctx, s_ctx, t_ctx, mask_ctx, x_test, s_test, t_test, rn_ws, keys);
        knn_v5_merge<<<dim3(kNQ / WAVES), dim3(256), 0, stream>>>(
            x_ctx, s_ctx, t_ctx, mask_ctx, x_test, s_test, t_test, keys,
            (float*)d_out);
    } else {
        knn_v4<<<dim3(kNQ / QPB), dim3(256), 0, stream>>>(
            x_ctx, s_ctx, t_ctx, mask_ctx, x_test, s_test, t_test, (float*)d_out);
    }
}

// Round 8
// 370.714 us; speedup vs baseline: 1.3727x; 1.3727x over previous
//
#include <hip/hip_runtime.h>

namespace {
constexpr int kB  = 2;
constexpr int kNC = 4096;
constexpr int kNT = 1024;
constexpr int kDX = 64;
constexpr int kK  = 32;
constexpr int kNQ = kB * (kNC + kNT);            // 10240
constexpr long long kE = (long long)kNQ * kK;    // 327680
constexpr int QPW  = 4;                          // queries per wave
constexpr int WAVES = 4;                         // waves per block
constexpr int QPB  = WAVES * QPW;                // 16 queries per block
constexpr int TILE = 64;                         // refs per LDS tile
constexpr int HALF = 2048;                       // refs per split-K block
constexpr int HT   = HALF / TILE;                // 32 tiles per half
// inf stand-in: must stay finite after bf16 round-trip (FLT_MAX -> bf16 inf)
constexpr float kBigFinite = 1e30f;
// ws layout: rn[8192] floats, then keys[kNQ][2][32] u64
constexpr size_t kRNF     = 8192;
constexpr size_t kKeyOffB = kRNF * 4;
constexpr size_t kWsNeed  = kKeyOffB + (size_t)kNQ * 64 * 8;
}

__device__ __forceinline__ void resolve_q(int gid,
    const float* x_ctx, const float* s_ctx, const float* t_ctx,
    const float* x_test, const float* s_test, const float* t_test,
    int& b, const float*& qx, const float*& qs, const float*& qt)
{
    if (gid < kB * kNC) {
        b  = gid >> 12;
        qx = x_ctx + (size_t)gid * kDX;
        qs = s_ctx + (size_t)gid * 3;
        qt = t_ctx + gid;
    } else {
        const int g2 = gid - kB * kNC;
        b  = g2 >> 10;
        qx = x_test + (size_t)g2 * kDX;
        qs = s_test + (size_t)g2 * 3;
        qt = t_test + g2;
    }
}

// Exact online insert into wave-held sorted ascending top-32 (validated r4-r7).
__device__ __forceinline__ void insert_half(unsigned long long& listKey,
    unsigned long long keyQ, int lane, int base)
{
    const unsigned long long thr = __shfl(listKey, base + 31, 64);
    unsigned long long hb = __ballot(keyQ < thr);
    while (hb) {
        const int srcl = __ffsll((unsigned long long)hb) - 1;
        hb &= hb - 1;
        const unsigned long long K = __shfl(keyQ, srcl, 64);
        const unsigned long long lt = __ballot(listKey < K);
        const unsigned int half = base ? (unsigned int)(lt >> 32)
                                       : (unsigned int)lt;
        const int pos = __popc(half) + base;
        if (pos < base + 32) {
            const unsigned long long up = __shfl_up(listKey, 1, 64);
            if (lane >= base && lane < base + 32) {
                if (lane > pos)       listKey = up;
                else if (lane == pos) listKey = K;
            }
        }
    }
}

// ---- prep: rn[row] with the exact validated fmaf chain (validated r5/r7) ----
__global__ __launch_bounds__(256)
void prep_rn(const float* __restrict__ x, float* __restrict__ ws)
{
    const int r = blockIdx.x * 256 + threadIdx.x;    // 0..8191
    const float4* xr = (const float4*)(x + (size_t)r * kDX);
    float rn = 0.f;
    #pragma unroll
    for (int j = 0; j < 16; ++j) {
        const float4 rv = xr[j];
        rn = fmaf(rv.x, rv.x, rn); rn = fmaf(rv.y, rv.y, rn);
        rn = fmaf(rv.z, rv.z, rn); rn = fmaf(rv.w, rv.w, rn);
    }
    ws[r] = rn;
}

// ---- split-K main: each block scans HALF refs for 16 queries, emits keys ----
// NOTE: launch_bounds (256,4) — validated no-spill point (r6: VGPR=64).
// (256,5) in r7 forced VGPR=48 -> 492MB scratch spill traffic, regression.
__global__ __launch_bounds__(256, 4)
void knn_v6_part(const float* __restrict__ x_ctx, const float* __restrict__ s_ctx,
                 const float* __restrict__ t_ctx, const unsigned char* __restrict__ mask_ctx,
                 const float* __restrict__ x_test, const float* __restrict__ s_test,
                 const float* __restrict__ t_test, const float* __restrict__ rn_ws,
                 unsigned long long* __restrict__ keys)
{
    __shared__ float4 xt[2][TILE * 16];   // 2 x 16KB double-buffered ref tiles

    const int tid  = threadIdx.x;
    const int lane = tid & 63;
    const int w    = __builtin_amdgcn_readfirstlane(tid >> 6);
    const int blk  = blockIdx.x;          // 1280
    const int g    = blk >> 1;            // query group 0..639
    const int h    = blk & 1;             // ref half
    const int qbase = g * QPB;
    const int gid0  = qbase + w * QPW;

    int b;
    { int b_; const float *a, *c, *d;
      resolve_q(qbase, x_ctx, s_ctx, t_ctx, x_test, s_test, t_test, b_, a, c, d);
      b = b_; }

    const float4* xb4 = (const float4*)x_ctx + (size_t)b * kNC * (kDX / 4);
    const float*  rsp = s_ctx + (size_t)b * kNC * 3;
    const float*  rtp = t_ctx + (size_t)b * kNC;
    const float*  rnp = rn_ws + (size_t)b * kNC;
    const unsigned char* mp = mask_ctx + (size_t)b * kNC;

    // ---- per-wave query setup (4 queries; pointers wave-uniform) ----
    const float* qxp[QPW];
    float qs0[QPW], qs1[QPW], qs2[QPW], qsn[QPW], qtv[QPW], qn[QPW];
    #pragma unroll
    for (int q = 0; q < QPW; ++q) {
        int bb; const float *qx, *qs, *qt;
        resolve_q(gid0 + q, x_ctx, s_ctx, t_ctx, x_test, s_test, t_test,
                  bb, qx, qs, qt);
        qxp[q] = qx;
        qs0[q] = qs[0]; qs1[q] = qs[1]; qs2[q] = qs[2]; qtv[q] = qt[0];
        qsn[q] = qs0[q]*qs0[q] + qs1[q]*qs1[q] + qs2[q]*qs2[q];
        const float ql = qx[lane];
        float s = ql * ql;
        #pragma unroll
        for (int off = 32; off > 0; off >>= 1) s += __shfl_xor(s, off, 64);
        qn[q] = s;
    }

    // staging geometry: 4 float4 per thread per tile, XOR-swizzled LDS dest
    int sg[4], ss[4];
    #pragma unroll
    for (int i = 0; i < 4; ++i) {
        const int n = tid + 256 * i;
        const int r = n >> 4, j = n & 15;
        sg[i] = n;
        ss[i] = (r << 4) | (j ^ (r & 7));
    }
    const size_t hbase = (size_t)h * (HALF * 16);   // float4 offset of this half
    #pragma unroll
    for (int i = 0; i < 4; ++i) xt[0][ss[i]] = xb4[hbase + sg[i]];
    __syncthreads();

    const int lbase = lane << 4, lsw = lane & 7;
    const float INF = __builtin_inff();
    unsigned long long lst01 = ~0ull, lst23 = ~0ull;

    for (int t = 0; t < HT; ++t) {
        float4 p0, p1, p2, p3;
        const bool pre = (t + 1 < HT);
        if (pre) {
            const size_t nb = hbase + (size_t)(t + 1) * 1024;
            p0 = xb4[nb + sg[0]]; p1 = xb4[nb + sg[1]];
            p2 = xb4[nb + sg[2]]; p3 = xb4[nb + sg[3]];
        }
        const float4* buf = xt[t & 1];

        float dot[QPW] = {0.f, 0.f, 0.f, 0.f};
        #pragma unroll
        for (int j = 0; j < 16; ++j) {
            const float4 rv = buf[lbase | (j ^ lsw)];
            #pragma unroll
            for (int q = 0; q < QPW; ++q) {
                const float4 qv = ((const float4*)qxp[q])[j];   // s_load (uniform)
                dot[q] = fmaf(qv.x, rv.x, dot[q]);
                dot[q] = fmaf(qv.y, rv.y, dot[q]);
                dot[q] = fmaf(qv.z, rv.z, dot[q]);
                dot[q] = fmaf(qv.w, rv.w, dot[q]);
            }
        }

        const int r = h * HALF + t * TILE + lane;
        const float rn  = rnp[r];                       // exact chain via prep_rn
        const float rs0 = rsp[r*3+0], rs1 = rsp[r*3+1], rs2 = rsp[r*3+2];
        const float rtv = rtp[r];
        const bool  m   = (mp[r] != 0);
        const float rsn = rs0*rs0 + rs1*rs1 + rs2*rs2;

        #pragma unroll
        for (int q = 0; q < QPW; ++q) {
            float d_x = qn[q] + rn - 2.0f * dot[q];
            const float sdot = qs0[q]*rs0 + qs1[q]*rs1 + qs2[q]*rs2;
            float d_s = qsn[q] + rsn - 2.0f * sdot;
            float d_t = rtv - qtv[q];
            if (!m) { d_x = INF; d_s = INF; d_t = INF; }
            if (!(d_t <= 0.f)) d_t = INF;
            const float v = d_x*d_x + d_s*d_s + d_t*d_t;
            const unsigned long long key =
                ((unsigned long long)__float_as_uint(v) << 32) | (unsigned)r;
            if (q < 2) insert_half(lst01, key, lane, (q & 1) * 32);
            else       insert_half(lst23, key, lane, (q & 1) * 32);
        }

        if (pre) {
            float4* nbuf = xt[(t + 1) & 1];
            nbuf[ss[0]] = p0; nbuf[ss[1]] = p1;
            nbuf[ss[2]] = p2; nbuf[ss[3]] = p3;
        }
        __syncthreads();
    }

    // ---- write per-half sorted key lists: keys[gid][h][slot] ----
    #pragma unroll
    for (int p = 0; p < 2; ++p) {
        const unsigned long long key = p ? lst23 : lst01;
        const int qidx = 2 * p + (lane >> 5);
        keys[((size_t)(gid0 + qidx) * 2 + h) * 32 + (lane & 31)] = key;
    }
}

// ---- merge two sorted 32-lists per query + validated emit (validated r7) ----
__global__ __launch_bounds__(256)
void knn_v5_merge(const float* __restrict__ x_ctx, const float* __restrict__ s_ctx,
                  const float* __restrict__ t_ctx, const unsigned char* __restrict__ mask_ctx,
                  const float* __restrict__ x_test, const float* __restrict__ s_test,
                  const float* __restrict__ t_test,
                  const unsigned long long* __restrict__ keys,
                  float* __restrict__ out)
{
    __shared__ unsigned long long kbuf[WAVES][64];
    __shared__ unsigned long long merged[WAVES][32];

    const int tid  = threadIdx.x;
    const int lane = tid & 63;
    const int w    = tid >> 6;
    const int qid  = blockIdx.x * WAVES + w;    // grid 2560 -> 10240 queries

    int b; const float *qx, *qs, *qt;
    resolve_q(qid, x_ctx, s_ctx, t_ctx, x_test, s_test, t_test, b, qx, qs, qt);
    const float qs0_ = qs[0], qs1_ = qs[1], qs2_ = qs[2], qtv_ = qt[0];
    const float qsn_ = qs0_*qs0_ + qs1_*qs1_ + qs2_*qs2_;
    const float ql = qx[lane];
    float qn_ = ql * ql;
    #pragma unroll
    for (int off = 32; off > 0; off >>= 1) qn_ += __shfl_xor(qn_, off, 64);

    // lane<32 holds half-0 list, lane>=32 holds half-1 list (both ascending)
    const unsigned long long mykey = keys[(size_t)qid * 64 + lane];
    kbuf[w][lane] = mykey;
    __syncthreads();

    int cnt = 0;
    const int ob = (lane < 32) ? 32 : 0;
    #pragma unroll
    for (int j = 0; j < 32; ++j) cnt += (kbuf[w][ob + j] < mykey) ? 1 : 0;
    const int pos = (lane & 31) + cnt;          // global rank (keys unique)
    if (pos < 32) merged[w][pos] = mykey;
    __syncthreads();

    if (lane < kK) {
        const unsigned long long key = merged[w][lane];
        const int rsel = (int)(key & 0xFFFFFFFFull);

        const float*  rsp = s_ctx + (size_t)b * kNC * 3;
        const float*  rtp = t_ctx + (size_t)b * kNC;
        const unsigned char* mp = mask_ctx + (size_t)b * kNC;

        const float4* xr = (const float4*)(x_ctx + ((size_t)b * kNC + rsel) * kDX);
        const float4* qr = (const float4*)qx;
        float dot = 0.f, rn2 = 0.f;
        #pragma unroll
        for (int j = 0; j < 16; ++j) {
            const float4 rv = xr[j];
            const float4 qv = qr[j];
            rn2 = fmaf(rv.x, rv.x, rn2); rn2 = fmaf(rv.y, rv.y, rn2);
            rn2 = fmaf(rv.z, rv.z, rn2); rn2 = fmaf(rv.w, rv.w, rn2);
            dot = fmaf(qv.x, rv.x, dot); dot = fmaf(qv.y, rv.y, dot);
            dot = fmaf(qv.z, rv.z, dot); dot = fmaf(qv.w, rv.w, dot);
        }
        float d_x = qn_ + rn2 - 2.0f * dot;
        const float rs0 = rsp[rsel*3+0], rs1 = rsp[rsel*3+1], rs2 = rsp[rsel*3+2];
        const float rsn = rs0*rs0 + rs1*rs1 + rs2*rs2;
        const float sdot = qs0_*rs0 + qs1_*rs1 + qs2_*rs2;
        float d_s = qsn_ + rsn - 2.0f * sdot;
        const float dt_raw = rtp[rsel] - qtv_;
        const bool  m = (mp[rsel] != 0);
        const bool  causal = m && (dt_raw <= 0.f);

        const float em = causal ? 1.0f : 0.0f;
        const float d_x_out = m ? d_x : kBigFinite;
        const float d_s_out = m ? d_s : kBigFinite;
        const float d_t_out = causal ? dt_raw : kBigFinite;

        const size_t e = (size_t)qid * kK + (size_t)lane;
        out[e]                = (float)(rsel + b * kNC);
        out[(size_t)kE   + e] = (float)qid;
        out[(size_t)kE*2 + e] = d_x_out;
        out[(size_t)kE*3 + e] = d_s_out;
        out[(size_t)kE*4 + e] = d_t_out;
        out[(size_t)kE*5 + e] = em;
    }
}

// ================= fallback: validated round-6 kernel (v4) =================
__global__ __launch_bounds__(256, 4)
void knn_v4(const float* __restrict__ x_ctx, const float* __restrict__ s_ctx,
            const float* __restrict__ t_ctx, const unsigned char* __restrict__ mask_ctx,
            const float* __restrict__ x_test, const float* __restrict__ s_test,
            const float* __restrict__ t_test, float* __restrict__ out)
{
    __shared__ float4 xt[2][TILE * 16];
    const int tid  = threadIdx.x;
    const int lane = tid & 63;
    const int w    = __builtin_amdgcn_readfirstlane(tid >> 6);
    const int qbase = blockIdx.x * QPB;
    const int gid0  = qbase + w * QPW;
    int b;
    { int b_; const float *a, *c, *d;
      resolve_q(qbase, x_ctx, s_ctx, t_ctx, x_test, s_test, t_test, b_, a, c, d);
      b = b_; }
    const float4* xb4 = (const float4*)x_ctx + (size_t)b * kNC * (kDX / 4);
    const float*  rsp = s_ctx + (size_t)b * kNC * 3;
    const float*  rtp = t_ctx + (size_t)b * kNC;
    const unsigned char* mp = mask_ctx + (size_t)b * kNC;
    const float* qxp[QPW];
    float qs0[QPW], qs1[QPW], qs2[QPW], qsn[QPW], qtv[QPW], qn[QPW];
    #pragma unroll
    for (int q = 0; q < QPW; ++q) {
        int bb; const float *qx, *qs, *qt;
        resolve_q(gid0 + q, x_ctx, s_ctx, t_ctx, x_test, s_test, t_test, bb, qx, qs, qt);
        qxp[q] = qx;
        qs0[q] = qs[0]; qs1[q] = qs[1]; qs2[q] = qs[2]; qtv[q] = qt[0];
        qsn[q] = qs0[q]*qs0[q] + qs1[q]*qs1[q] + qs2[q]*qs2[q];
        const float ql = qx[lane];
        float s = ql * ql;
        #pragma unroll
        for (int off = 32; off > 0; off >>= 1) s += __shfl_xor(s, off, 64);
        qn[q] = s;
    }
    int sg[4], ss[4];
    #pragma unroll
    for (int i = 0; i < 4; ++i) {
        const int n = tid + 256 * i;
        const int r = n >> 4, j = n & 15;
        sg[i] = n; ss[i] = (r << 4) | (j ^ (r & 7));
    }
    #pragma unroll
    for (int i = 0; i < 4; ++i) xt[0][ss[i]] = xb4[sg[i]];
    __syncthreads();
    const int lbase = lane << 4, lsw = lane & 7;
    const float INF = __builtin_inff();
    unsigned long long lst01 = ~0ull, lst23 = ~0ull;
    for (int t = 0; t < kNC / TILE; ++t) {
        float4 p0, p1, p2, p3;
        const bool pre = (t + 1 < kNC / TILE);
        if (pre) {
            const size_t nb = (size_t)(t + 1) * 1024;
            p0 = xb4[nb + sg[0]]; p1 = xb4[nb + sg[1]];
            p2 = xb4[nb + sg[2]]; p3 = xb4[nb + sg[3]];
        }
        const float4* buf = xt[t & 1];
        float dot[QPW] = {0.f, 0.f, 0.f, 0.f};
        float rn = 0.f;
        #pragma unroll
        for (int j = 0; j < 16; ++j) {
            const float4 rv = buf[lbase | (j ^ lsw)];
            rn = fmaf(rv.x, rv.x, rn); rn = fmaf(rv.y, rv.y, rn);
            rn = fmaf(rv.z, rv.z, rn); rn = fmaf(rv.w, rv.w, rn);
            #pragma unroll
            for (int q = 0; q < QPW; ++q) {
                const float4 qv = ((const float4*)qxp[q])[j];
                dot[q] = fmaf(qv.x, rv.x, dot[q]);
                dot[q] = fmaf(qv.y, rv.y, dot[q]);
                dot[q] = fmaf(qv.z, rv.z, dot[q]);
                dot[q] = fmaf(qv.w, rv.w, dot[q]);
            }
        }
        const int r = t * TILE + lane;
        const float rs0 = rsp[r*3+0], rs1 = rsp[r*3+1], rs2 = rsp[r*3+2];
        const float rtv = rtp[r];
        const bool  m   = (mp[r] != 0);
        const float rsn = rs0*rs0 + rs1*rs1 + rs2*rs2;
        #pragma unroll
        for (int q = 0; q < QPW; ++q) {
            float d_x = qn[q] + rn - 2.0f * dot[q];
            const float sdot = qs0[q]*rs0 + qs1[q]*rs1 + qs2[q]*rs2;
            float d_s = qsn[q] + rsn - 2.0f * sdot;
            float d_t = rtv - qtv[q];
            if (!m) { d_x = INF; d_s = INF; d_t = INF; }
            if (!(d_t <= 0.f)) d_t = INF;
            const float v = d_x*d_x + d_s*d_s + d_t*d_t;
            const unsigned long long key =
                ((unsigned long long)__float_as_uint(v) << 32) | (unsigned)r;
            if (q < 2) insert_half(lst01, key, lane, (q & 1) * 32);
            else       insert_half(lst23, key, lane, (q & 1) * 32);
        }
        if (pre) {
            float4* nbuf = xt[(t + 1) & 1];
            nbuf[ss[0]] = p0; nbuf[ss[1]] = p1;
            nbuf[ss[2]] = p2; nbuf[ss[3]] = p3;
        }
        __syncthreads();
    }
    #pragma unroll
    for (int p = 0; p < 2; ++p) {
        const unsigned long long myl = p ? lst23 : lst01;
        const int qidx = 2 * p + (lane >> 5);
        const int rsel = (int)(myl & 0xFFFFFFFFull);
        const int gid  = gid0 + qidx;
        const float* qx  = (lane < 32) ? qxp[2*p] : qxp[2*p+1];
        const float qn_  = (lane < 32) ? qn [2*p] : qn [2*p+1];
        const float qs0_ = (lane < 32) ? qs0[2*p] : qs0[2*p+1];
        const float qs1_ = (lane < 32) ? qs1[2*p] : qs1[2*p+1];
        const float qs2_ = (lane < 32) ? qs2[2*p] : qs2[2*p+1];
        const float qsn_ = (lane < 32) ? qsn[2*p] : qsn[2*p+1];
        const float qtv_ = (lane < 32) ? qtv[2*p] : qtv[2*p+1];
        const float4* xr = (const float4*)(x_ctx + ((size_t)b * kNC + rsel) * kDX);
        const float4* qr = (const float4*)qx;
        float dot = 0.f, rn2 = 0.f;
        #pragma unroll
        for (int j = 0; j < 16; ++j) {
            const float4 rv = xr[j];
            const float4 qv = qr[j];
            rn2 = fmaf(rv.x, rv.x, rn2); rn2 = fmaf(rv.y, rv.y, rn2);
            rn2 = fmaf(rv.z, rv.z, rn2); rn2 = fmaf(rv.w, rv.w, rn2);
            dot = fmaf(qv.x, rv.x, dot); dot = fmaf(qv.y, rv.y, dot);
            dot = fmaf(qv.z, rv.z, dot); dot = fmaf(qv.w, rv.w, dot);
        }
        float d_x = qn_ + rn2 - 2.0f * dot;
        const float rs0 = rsp[rsel*3+0], rs1 = rsp[rsel*3+1], rs2 = rsp[rsel*3+2];
        const float rsn = rs0*rs0 + rs1*rs1 + rs2*rs2;
        const float sdot = qs0_*rs0 + qs1_*rs1 + qs2_*rs2;
        float d_s = qsn_ + rsn - 2.0f * sdot;
        const float dt_raw = rtp[rsel] - qtv_;
        const bool  m = (mp[rsel] != 0);
        const bool  causal = m && (dt_raw <= 0.f);
        const float em = causal ? 1.0f : 0.0f;
        const size_t e = (size_t)gid * kK + (size_t)(lane & 31);
        out[e]                = (float)(rsel + b * kNC);
        out[(size_t)kE   + e] = (float)gid;
        out[(size_t)kE*2 + e] = m ? d_x : kBigFinite;
        out[(size_t)kE*3 + e] = m ? d_s : kBigFinite;
        out[(size_t)kE*4 + e] = causal ? dt_raw : kBigFinite;
        out[(size_t)kE*5 + e] = em;
    }
}

extern "C" void kernel_launch(void* const* d_in, const int* in_sizes, int n_in,
                              void* d_out, int out_size, void* d_ws, size_t ws_size,
                              hipStream_t stream) {
    (void)in_sizes; (void)n_in; (void)out_size;
    const float* x_ctx = (const float*)d_in[0];
    const float* s_ctx = (const float*)d_in[1];
    const float* t_ctx = (const float*)d_in[2];
    const unsigned char* mask_ctx = (const unsigned char*)d_in[3];
    const float* x_test = (const float*)d_in[4];
    const float* s_test = (const float*)d_in[5];
    const float* t_test = (const float*)d_in[6];

    if (ws_size >= kWsNeed) {
        float* rn_ws = (float*)d_ws;
        unsigned long long* keys =
            (unsigned long long*)((char*)d_ws + kKeyOffB);
        prep_rn<<<dim3(32), dim3(256), 0, stream>>>(x_ctx, rn_ws);
        knn_v6_part<<<dim3(2 * kNQ / QPB), dim3(256), 0, stream>>>(
            x_ctx, s_ctx, t_ctx, mask_ctx, x_test, s_test, t_test, rn_ws, keys);
        knn_v5_merge<<<dim3(kNQ / WAVES), dim3(256), 0, stream>>>(
            x_ctx, s_ctx, t_ctx, mask_ctx, x_test, s_test, t_test, keys,
            (float*)d_out);
    } else {
        knn_v4<<<dim3(kNQ / QPB), dim3(256), 0, stream>>>(
            x_ctx, s_ctx, t_ctx, mask_ctx, x_test, s_test, t_test, (float*)d_out);
    }
}